// Round 1
// baseline (2639.891 us; speedup 1.0000x reference)
//
#include <hip/hip_runtime.h>

constexpr int NN = 100000;   // nodes
constexpr int NE = 1600000;  // edges
constexpr int NG = 5000;     // graphs

// ---------------- zero workspace ----------------
__global__ __launch_bounds__(256) void k_zero(float4* p, int n4) {
  int i = blockIdx.x * 256 + threadIdx.x;
  if (i < n4) p[i] = make_float4(0.f, 0.f, 0.f, 0.f);
}

// ---------------- edge MLP + scatter to nodes ----------------
// msg = relu([na[src], na[dst], ea[e]] @ Wm + bm);  x[dst] += msg
__global__ __launch_bounds__(256) void k_edge(
    const int* __restrict__ ei,
    const float* __restrict__ nattr,
    const float* __restrict__ eattr,
    const float* __restrict__ Wm,
    const float* __restrict__ bm,
    float* __restrict__ x) {
  __shared__ float Wl[960];   // 48 x 20
  __shared__ float bl[20];
  for (int i = threadIdx.x; i < 960; i += 256) Wl[i] = Wm[i];
  if (threadIdx.x < 20) bl[threadIdx.x] = bm[threadIdx.x];
  __syncthreads();

  int e = blockIdx.x * 256 + threadIdx.x;
  if (e >= NE) return;
  int src = ei[e];
  int dst = ei[NE + e];

  alignas(16) float f[48];
  float4* fv = (float4*)f;
  const float4* ps = (const float4*)(nattr + (size_t)src * 16);
  const float4* pd = (const float4*)(nattr + (size_t)dst * 16);
  const float4* pe = (const float4*)(eattr + (size_t)e * 16);
  fv[0] = ps[0]; fv[1] = ps[1]; fv[2]  = ps[2]; fv[3]  = ps[3];
  fv[4] = pd[0]; fv[5] = pd[1]; fv[6]  = pd[2]; fv[7]  = pd[3];
  fv[8] = pe[0]; fv[9] = pe[1]; fv[10] = pe[2]; fv[11] = pe[3];

  float acc[20];
#pragma unroll
  for (int j = 0; j < 20; ++j) acc[j] = bl[j];
#pragma unroll
  for (int k = 0; k < 48; ++k) {
    float fk = f[k];
#pragma unroll
    for (int jv = 0; jv < 5; ++jv) {
      // uniform LDS address across the wave -> broadcast, no bank cost
      float4 w = *(const float4*)&Wl[k * 20 + jv * 4];
      acc[jv*4+0] = fmaf(fk, w.x, acc[jv*4+0]);
      acc[jv*4+1] = fmaf(fk, w.y, acc[jv*4+1]);
      acc[jv*4+2] = fmaf(fk, w.z, acc[jv*4+2]);
      acc[jv*4+3] = fmaf(fk, w.w, acc[jv*4+3]);
    }
  }

  float* xd = x + (size_t)dst * 20;
#pragma unroll
  for (int j = 0; j < 20; ++j) {
    float m = fmaxf(acc[j], 0.f);
    if (m > 0.f) atomicAdd(xd + j, m);  // skip zeros: ~halves atomic traffic
  }
}

// ---------------- node MLP + pool to graphs ----------------
// y = relu(x @ W1 + b1);  g[batch[n]] += y
__global__ __launch_bounds__(256) void k_node(
    const float* __restrict__ x,
    const int* __restrict__ batch,
    const float* __restrict__ W1,
    const float* __restrict__ b1,
    float* __restrict__ g) {
  __shared__ float Wl[200];   // 20 x 10
  __shared__ float bl[10];
  if (threadIdx.x < 200) Wl[threadIdx.x] = W1[threadIdx.x];
  if (threadIdx.x < 10) bl[threadIdx.x] = b1[threadIdx.x];
  __syncthreads();

  int n = blockIdx.x * 256 + threadIdx.x;
  if (n >= NN) return;

  alignas(16) float xi[20];
  float4* xv = (float4*)xi;
  const float4* px = (const float4*)(x + (size_t)n * 20);  // 80B rows -> 16B aligned
#pragma unroll
  for (int i = 0; i < 5; ++i) xv[i] = px[i];

  float acc[10];
#pragma unroll
  for (int j = 0; j < 10; ++j) acc[j] = bl[j];
#pragma unroll
  for (int k = 0; k < 20; ++k) {
    float fk = xi[k];
#pragma unroll
    for (int j = 0; j < 10; ++j) acc[j] = fmaf(fk, Wl[k * 10 + j], acc[j]);
  }

  int b = batch[n];
  float* gd = g + (size_t)b * 10;
#pragma unroll
  for (int j = 0; j < 10; ++j) {
    float m = fmaxf(acc[j], 0.f);
    if (m > 0.f) atomicAdd(gd + j, m);
  }
}

// ---------------- graph MLP ----------------
// out = relu(g @ W2 + b2) @ W3 + b3
__global__ __launch_bounds__(256) void k_graph(
    const float* __restrict__ g,
    const float* __restrict__ W2, const float* __restrict__ b2,
    const float* __restrict__ W3, const float* __restrict__ b3,
    float* __restrict__ out) {
  __shared__ float W2l[100], b2l[10], W3l[10];
  __shared__ float b3l;
  if (threadIdx.x < 100) W2l[threadIdx.x] = W2[threadIdx.x];
  if (threadIdx.x < 10) { b2l[threadIdx.x] = b2[threadIdx.x]; W3l[threadIdx.x] = W3[threadIdx.x]; }
  if (threadIdx.x == 0) b3l = b3[0];
  __syncthreads();

  int i = blockIdx.x * 256 + threadIdx.x;
  if (i >= NG) return;

  float gi[10];
  const float2* pg = (const float2*)(g + (size_t)i * 10);  // 40B rows -> 8B aligned
#pragma unroll
  for (int k = 0; k < 5; ++k) { float2 v = pg[k]; gi[2*k] = v.x; gi[2*k+1] = v.y; }

  float o = b3l;
#pragma unroll
  for (int j = 0; j < 10; ++j) {
    float a = b2l[j];
#pragma unroll
    for (int k = 0; k < 10; ++k) a = fmaf(gi[k], W2l[k * 10 + j], a);
    o = fmaf(fmaxf(a, 0.f), W3l[j], o);
  }
  out[i] = o;
}

extern "C" void kernel_launch(void* const* d_in, const int* in_sizes, int n_in,
                              void* d_out, int out_size, void* d_ws, size_t ws_size,
                              hipStream_t stream) {
  const int*   ei    = (const int*)  d_in[0];
  const float* nattr = (const float*)d_in[1];
  const float* eattr = (const float*)d_in[2];
  const int*   batch = (const int*)  d_in[3];
  const float* Wm    = (const float*)d_in[4];
  const float* bm    = (const float*)d_in[5];
  const float* W1    = (const float*)d_in[6];
  const float* b1    = (const float*)d_in[7];
  const float* W2    = (const float*)d_in[8];
  const float* b2    = (const float*)d_in[9];
  const float* W3    = (const float*)d_in[10];
  const float* b3    = (const float*)d_in[11];

  float* x = (float*)d_ws;             // [NN, 20] = 8,000,000 B
  float* g = x + (size_t)NN * 20;      // [NG, 10] =   200,000 B

  int n4 = (NN * 20 + NG * 10) / 4;    // 512,500 float4s, exact
  k_zero <<<(n4 + 255) / 256, 256, 0, stream>>>((float4*)d_ws, n4);
  k_edge <<<(NE + 255) / 256, 256, 0, stream>>>(ei, nattr, eattr, Wm, bm, x);
  k_node <<<(NN + 255) / 256, 256, 0, stream>>>(x, batch, W1, b1, g);
  k_graph<<<(NG + 255) / 256, 256, 0, stream>>>(g, W2, b2, W3, b3, (float*)d_out);
}